// Round 2
// baseline (241.350 us; speedup 1.0000x reference)
//
#include <hip/hip_runtime.h>
#include <hip/hip_bf16.h>

// Problem: B=4, N=2048, IN=256, H=8, ATN=32
//   xt = x@W + b            [B,H,N,32]
//   xC = xt @ C^T           [B,H,N,32]   (contract 2nd index of C)
//   S  = xC @ xt^T          [B,H,N,N]
//   alpha = tanh(S * adj)   [B,H,N,N]    (never materialized)
//   heads = alpha @ xt      [B,H,N,32] -> out [B,N,256] fp32
//
// R2 changes vs R1 (which was latency-bound: 21% occ, MfmaUtil 4.7%):
//   - k_attn: m-loop split into 4 chunks -> 1024 blocks -> 32 waves/CU,
//     barrier removed (alpha LDS is wave-private), chunks atomically
//     accumulate to out (unsafeAtomicAdd = native f32 atomic).
//   - k_proj: all global stores routed through LDS -> coalesced 16B stores
//     (R1's 2B-stride-4KB xtT scatter cost ~90 us).
//   - out zero-init folded into k_prep (harness poisons d_out each call).

typedef __bf16 bf16;
typedef __attribute__((ext_vector_type(8))) __bf16 bf16x8;
typedef __attribute__((ext_vector_type(4))) __bf16 bf16x4;
typedef __attribute__((ext_vector_type(4))) float  f32x4;

#define MFMA(a, b, c) __builtin_amdgcn_mfma_f32_16x16x32_bf16(a, b, c, 0, 0, 0)

// Padé tanh: x(945 + 105 t + t^2)/(945 + 420 t + 15 t^2), t = x^2, clamped.
__device__ __forceinline__ float fast_tanh(float x) {
    float t   = x * x;
    float num = x * __builtin_fmaf(t, t + 105.0f, 945.0f);
    float den = __builtin_fmaf(t, __builtin_fmaf(t, 15.0f, 420.0f), 945.0f);
    float r   = num * __builtin_amdgcn_rcpf(den);
    return __builtin_amdgcn_fmed3f(r, -1.0f, 1.0f);
}

#define BB   4
#define NN   2048
#define IND  256
#define HH   8
#define ATN  32

// workspace layout (bytes)
#define OFF_XBF  0u            // x as bf16 [B][N][IN]      (4 MB)
#define OFF_XT   4194304u      // xt  [B][H][N][32] bf16    (4 MB)
#define OFF_XC   8388608u      // xC  [B][H][N][32] bf16    (4 MB)
#define OFF_XTT  12582912u     // xt^T[B][H][32][N] bf16    (4 MB)
#define OFF_WT   16777216u     // W^T [H][32][256]  bf16    (128 KB)
#define OFF_CB   16908288u     // C   [H][32][32]   bf16    (16 KB)

// ---------------- kernel 0: dtype conversion + out zero ----------------
__global__ __launch_bounds__(256) void k_prep(const float* __restrict__ x,
                                              const float* __restrict__ W,
                                              const float* __restrict__ C,
                                              bf16* __restrict__ xbf,
                                              bf16* __restrict__ WT,
                                              bf16* __restrict__ Cb,
                                              float* __restrict__ out) {
    int tid = blockIdx.x * 256 + threadIdx.x;
    if (tid < 524288) {
        float4 v = ((const float4*)x)[tid];
        bf16x4 o;
        o[0] = (bf16)v.x; o[1] = (bf16)v.y; o[2] = (bf16)v.z; o[3] = (bf16)v.w;
        *(bf16x4*)(xbf + (size_t)tid * 4) = o;
    } else if (tid < 524288 + 65536) {
        int t = tid - 524288;
        int h = t >> 13, r = t & 8191, i = r >> 5, o = r & 31;
        WT[(h * 32 + o) * 256 + i] = (bf16)W[t];
    } else if (tid < 524288 + 65536 + 8192) {
        int t = tid - (524288 + 65536);
        Cb[t] = (bf16)C[t];
    } else if (tid < 598016 + 524288) {
        int t = tid - 598016;          // zero out[2M floats] as float4
        float4 z = {0.f, 0.f, 0.f, 0.f};
        ((float4*)out)[t] = z;
    }
}

// ---------------- kernel A: projection ----------------
// grid 2048 = b(4)*h(8)*ntile(64); 1 wave/block.
__global__ __launch_bounds__(64) void k_proj(const bf16* __restrict__ xbf,
                                             const bf16* __restrict__ WT,
                                             const bf16* __restrict__ Cb,
                                             const float* __restrict__ bias,
                                             bf16* __restrict__ xt,
                                             bf16* __restrict__ xc,
                                             bf16* __restrict__ xtT) {
    __shared__ bf16 ldsA[32 * 40];   // xt tile, stride 40 elems (16B-aligned rows)
    __shared__ bf16 ldsB[32 * 40];   // xc tile
    int bid = blockIdx.x;
    int nt = bid & 63, h = (bid >> 6) & 7, b = bid >> 9;
    int n0 = nt * 32;
    int lane = threadIdx.x;
    int c = lane & 15, q = lane >> 4;

    f32x4 acc[2][2] = {};
    const bf16* xrow0 = xbf + ((size_t)(b * NN + n0 + c) * IND + q * 8);
    const bf16* xrow1 = xbf + ((size_t)(b * NN + n0 + 16 + c) * IND + q * 8);
    const bf16* wrow0 = WT + ((h * 32 + c) * IND + q * 8);
    const bf16* wrow1 = WT + ((h * 32 + 16 + c) * IND + q * 8);
#pragma unroll
    for (int k0 = 0; k0 < IND; k0 += 32) {
        bf16x8 a0 = *(const bf16x8*)(xrow0 + k0);
        bf16x8 a1 = *(const bf16x8*)(xrow1 + k0);
        bf16x8 w0 = *(const bf16x8*)(wrow0 + k0);
        bf16x8 w1 = *(const bf16x8*)(wrow1 + k0);
        acc[0][0] = MFMA(a0, w0, acc[0][0]);
        acc[0][1] = MFMA(a0, w1, acc[0][1]);
        acc[1][0] = MFMA(a1, w0, acc[1][0]);
        acc[1][1] = MFMA(a1, w1, acc[1][1]);
    }
    float bv[2] = { bias[h * 32 + c], bias[h * 32 + 16 + c] };
    size_t bh = (size_t)(b * HH + h);
    // C/D layout: row(n_local) = q*4+r (+16*nq), col(o_local) = c (+16*oq)
#pragma unroll
    for (int nq = 0; nq < 2; ++nq)
#pragma unroll
        for (int oq = 0; oq < 2; ++oq)
#pragma unroll
            for (int r = 0; r < 4; ++r)
                ldsA[(nq * 16 + q * 4 + r) * 40 + oq * 16 + c] =
                    (bf16)(acc[nq][oq][r] + bv[oq]);
    // xC = xt @ C^T : B[k=o][col=p] = C[p][o] (row-major C)
    f32x4 acc2[2][2] = {};
    bf16x8 aL0 = *(const bf16x8*)(ldsA + (c) * 40 + q * 8);
    bf16x8 aL1 = *(const bf16x8*)(ldsA + (16 + c) * 40 + q * 8);
    bf16x8 c0 = *(const bf16x8*)(Cb + h * 1024 + (c) * 32 + q * 8);
    bf16x8 c1 = *(const bf16x8*)(Cb + h * 1024 + (16 + c) * 32 + q * 8);
    acc2[0][0] = MFMA(aL0, c0, acc2[0][0]);
    acc2[0][1] = MFMA(aL0, c1, acc2[0][1]);
    acc2[1][0] = MFMA(aL1, c0, acc2[1][0]);
    acc2[1][1] = MFMA(aL1, c1, acc2[1][1]);
#pragma unroll
    for (int nq = 0; nq < 2; ++nq)
#pragma unroll
        for (int pq = 0; pq < 2; ++pq)
#pragma unroll
            for (int r = 0; r < 4; ++r)
                ldsB[(nq * 16 + q * 4 + r) * 40 + pq * 16 + c] =
                    (bf16)acc2[nq][pq][r];

    // ---- coalesced stores from LDS ----
    // xt & xc: lane -> (row n = lane>>1, half = lane&1), 16 elems = 2x b128
    {
        int n = lane >> 1, half = lane & 1;
        bf16x8 t0 = *(const bf16x8*)(ldsA + n * 40 + half * 16);
        bf16x8 t1 = *(const bf16x8*)(ldsA + n * 40 + half * 16 + 8);
        bf16* dst = xt + (bh * NN + n0 + n) * ATN + half * 16;
        *(bf16x8*)(dst) = t0;
        *(bf16x8*)(dst + 8) = t1;
        bf16x8 u0 = *(const bf16x8*)(ldsB + n * 40 + half * 16);
        bf16x8 u1 = *(const bf16x8*)(ldsB + n * 40 + half * 16 + 8);
        bf16* dst2 = xc + (bh * NN + n0 + n) * ATN + half * 16;
        *(bf16x8*)(dst2) = u0;
        *(bf16x8*)(dst2 + 8) = u1;
    }
    // xtT: lane -> (o = lane>>1, nh = lane&1); gather column o from LDS
    {
        int o = lane >> 1, nh = lane & 1;
        bf16x8 t0, t1;
#pragma unroll
        for (int i = 0; i < 8; ++i) {
            t0[i] = ldsA[(nh * 16 + i) * 40 + o];
            t1[i] = ldsA[(nh * 16 + 8 + i) * 40 + o];
        }
        bf16* dst = xtT + (bh * ATN + o) * NN + n0 + nh * 16;
        *(bf16x8*)(dst) = t0;
        *(bf16x8*)(dst + 8) = t1;
    }
}

// ---------------- kernel B: fused scores/tanh/PV ----------------
// grid 1024 = chunk(4) * b(4) * ntile(64); 512 thr = 8 waves; wave == head.
// Each block: n-tile of 32, m in [chunk*512, chunk*512+512). No barrier
// (alpha LDS is wave-private). Chunks accumulate out via native f32 atomics.
__global__ __launch_bounds__(512, 8) void k_attn(const float* __restrict__ adj,
                                                 const bf16* __restrict__ xt,
                                                 const bf16* __restrict__ xc,
                                                 const bf16* __restrict__ xtT,
                                                 float* __restrict__ out) {
    __shared__ ushort alds[HH * 32 * 40];   // per-wave alpha tile, 80 B stride
    int bid = blockIdx.x;
    int chunk = bid >> 8;
    int bn = bid & 255;
    int nt = bn & 63, b = bn >> 6;
    int n0 = nt * 32;
    int wave = threadIdx.x >> 6;            // == head
    int lane = threadIdx.x & 63;
    int c = lane & 15, q = lane >> 4;
    size_t bh = (size_t)(b * HH + wave);
    const bf16* xt_h = xt + bh * NN * ATN;
    const bf16* xc_h = xc + bh * NN * ATN;
    const bf16* xtT_h = xtT + bh * ATN * NN;
    const float* adj_b = adj + (size_t)b * NN * NN;
    bf16* al = (bf16*)(alds + wave * 32 * 40);

    // scores B-operand: B[k=p][col=n] = xC[n][p], fixed n-tile -> preload
    bf16x8 bXC0 = *(const bf16x8*)(xc_h + (n0 + c) * ATN + q * 8);
    bf16x8 bXC1 = *(const bf16x8*)(xc_h + (n0 + 16 + c) * ATN + q * 8);
    f32x4 accO[2][2] = {};
    const f32x4 z = {0.f, 0.f, 0.f, 0.f};

    int m_beg = chunk * 512, m_end = m_beg + 512;
    for (int m0 = m_beg; m0 < m_end; m0 += 32) {
        bf16x8 aXT0 = *(const bf16x8*)(xt_h + (m0 + c) * ATN + q * 8);
        bf16x8 aXT1 = *(const bf16x8*)(xt_h + (m0 + 16 + c) * ATN + q * 8);
        f32x4 S[2][2];
        S[0][0] = MFMA(aXT0, bXC0, z);
        S[0][1] = MFMA(aXT0, bXC1, z);
        S[1][0] = MFMA(aXT1, bXC0, z);
        S[1][1] = MFMA(aXT1, bXC1, z);
        // S' D layout: row = m_local = q*4+r (+16mq), col = n_local = c (+16nq)
#pragma unroll
        for (int mq = 0; mq < 2; ++mq)
#pragma unroll
            for (int nq = 0; nq < 2; ++nq) {
                f32x4 av = *(const f32x4*)(adj_b +
                    (size_t)(n0 + nq * 16 + c) * NN + m0 + mq * 16 + q * 4);
                bf16x4 pk;
#pragma unroll
                for (int r = 0; r < 4; ++r)
                    pk[r] = (bf16)fast_tanh(S[mq][nq][r] * av[r]);
                *(bf16x4*)(al + (nq * 16 + c) * 40 + mq * 16 + q * 4) = pk;
            }
        // PV: A[n][k=m] from LDS, B[k=m][col=o] = xtT[o][m]
        bf16x8 aAL0 = *(const bf16x8*)(al + (c) * 40 + q * 8);
        bf16x8 aAL1 = *(const bf16x8*)(al + (16 + c) * 40 + q * 8);
        bf16x8 bXT0 = *(const bf16x8*)(xtT_h + (c) * NN + m0 + q * 8);
        bf16x8 bXT1 = *(const bf16x8*)(xtT_h + (16 + c) * NN + m0 + q * 8);
        accO[0][0] = MFMA(aAL0, bXT0, accO[0][0]);
        accO[0][1] = MFMA(aAL0, bXT1, accO[0][1]);
        accO[1][0] = MFMA(aAL1, bXT0, accO[1][0]);
        accO[1][1] = MFMA(aAL1, bXT1, accO[1][1]);
    }
    // epilogue: accumulate across chunks with native f32 atomics
#pragma unroll
    for (int nq = 0; nq < 2; ++nq)
#pragma unroll
        for (int oq = 0; oq < 2; ++oq)
#pragma unroll
            for (int r = 0; r < 4; ++r) {
                int n = n0 + nq * 16 + q * 4 + r;
                int o = wave * 32 + oq * 16 + c;
                unsafeAtomicAdd(&out[((size_t)b * NN + n) * (HH * ATN) + o],
                                accO[nq][oq][r]);
            }
}

extern "C" void kernel_launch(void* const* d_in, const int* in_sizes, int n_in,
                              void* d_out, int out_size, void* d_ws, size_t ws_size,
                              hipStream_t stream) {
    const float* x    = (const float*)d_in[0];   // [4,2048,256]
    const float* adj  = (const float*)d_in[1];   // [4,2048,2048]
    const float* W    = (const float*)d_in[2];   // [8,256,32]
    const float* bias = (const float*)d_in[3];   // [8,32]
    const float* C    = (const float*)d_in[4];   // [8,32,32]
    float* out = (float*)d_out;                  // [4,2048,256]

    char* ws = (char*)d_ws;                      // ~16.9 MB
    bf16* xbf = (bf16*)(ws + OFF_XBF);
    bf16* xt  = (bf16*)(ws + OFF_XT);
    bf16* xc  = (bf16*)(ws + OFF_XC);
    bf16* xtT = (bf16*)(ws + OFF_XTT);
    bf16* WT  = (bf16*)(ws + OFF_WT);
    bf16* Cb  = (bf16*)(ws + OFF_CB);

    k_prep<<<4384, 256, 0, stream>>>(x, W, C, xbf, WT, Cb, out);
    k_proj<<<2048, 64, 0, stream>>>(xbf, WT, Cb, bias, xt, xc, xtT);
    k_attn<<<1024, 512, 0, stream>>>(adj, xt, xc, xtT, out);
}

// Round 3
// 220.973 us; speedup vs baseline: 1.0922x; 1.0922x over previous
//
#include <hip/hip_runtime.h>
#include <hip/hip_bf16.h>

// Problem: B=4, N=2048, IN=256, H=8, ATN=32
//   xt = x@W + b            [B,H,N,32]
//   xC = xt @ C^T           [B,H,N,32]
//   S  = xC @ xt^T          [B,H,N,N]
//   alpha = tanh(S * adj)   [B,H,N,N]    (never materialized)
//   heads = alpha @ xt      [B,H,N,32] -> out [B,N,256] fp32
//
// R3: k_attn m-loop explicitly software-pipelined (register double-buffer
// for adj/xt/xtT loads, fully unrolled) — R2 showed occupancy 21->78% with
// ZERO dur change: per-wave serial chain (HBM adj load -> tanh -> LDS -> MFMA)
// dominates, so give every load a full iteration of in-flight time.
// k_proj fattened to 256-thread blocks (4 tiles/block).

typedef __bf16 bf16;
typedef __attribute__((ext_vector_type(8))) __bf16 bf16x8;
typedef __attribute__((ext_vector_type(4))) __bf16 bf16x4;
typedef __attribute__((ext_vector_type(4))) float  f32x4;

#define MFMA(a, b, c) __builtin_amdgcn_mfma_f32_16x16x32_bf16(a, b, c, 0, 0, 0)

// Padé tanh: x(945 + 105 t + t^2)/(945 + 420 t + 15 t^2), t = x^2, clamped.
__device__ __forceinline__ float fast_tanh(float x) {
    float t   = x * x;
    float num = x * __builtin_fmaf(t, t + 105.0f, 945.0f);
    float den = __builtin_fmaf(t, __builtin_fmaf(t, 15.0f, 420.0f), 945.0f);
    float r   = num * __builtin_amdgcn_rcpf(den);
    return __builtin_amdgcn_fmed3f(r, -1.0f, 1.0f);
}

#define BB   4
#define NN   2048
#define IND  256
#define HH   8
#define ATN  32

// workspace layout (bytes)
#define OFF_XBF  0u            // x as bf16 [B][N][IN]      (4 MB)
#define OFF_XT   4194304u      // xt  [B][H][N][32] bf16    (4 MB)
#define OFF_XC   8388608u      // xC  [B][H][N][32] bf16    (4 MB)
#define OFF_XTT  12582912u     // xt^T[B][H][32][N] bf16    (4 MB)
#define OFF_WT   16777216u     // W^T [H][32][256]  bf16    (128 KB)
#define OFF_CB   16908288u     // C   [H][32][32]   bf16    (16 KB)

// ---------------- kernel 0: dtype conversion + out zero ----------------
__global__ __launch_bounds__(256) void k_prep(const float* __restrict__ x,
                                              const float* __restrict__ W,
                                              const float* __restrict__ C,
                                              bf16* __restrict__ xbf,
                                              bf16* __restrict__ WT,
                                              bf16* __restrict__ Cb,
                                              float* __restrict__ out) {
    int tid = blockIdx.x * 256 + threadIdx.x;
    if (tid < 524288) {
        float4 v = ((const float4*)x)[tid];
        bf16x4 o;
        o[0] = (bf16)v.x; o[1] = (bf16)v.y; o[2] = (bf16)v.z; o[3] = (bf16)v.w;
        *(bf16x4*)(xbf + (size_t)tid * 4) = o;
    } else if (tid < 524288 + 65536) {
        int t = tid - 524288;
        int h = t >> 13, r = t & 8191, i = r >> 5, o = r & 31;
        WT[(h * 32 + o) * 256 + i] = (bf16)W[t];
    } else if (tid < 524288 + 65536 + 8192) {
        int t = tid - (524288 + 65536);
        Cb[t] = (bf16)C[t];
    } else if (tid < 598016 + 524288) {
        int t = tid - 598016;          // zero out[2M floats] as float4
        float4 z = {0.f, 0.f, 0.f, 0.f};
        ((float4*)out)[t] = z;
    }
}

// ---------------- kernel A: projection ----------------
// grid 512 = b(4)*h(8)*ntg(16); 256 thr = 4 waves; wave w -> nt = ntg*4+w.
__global__ __launch_bounds__(256) void k_proj(const bf16* __restrict__ xbf,
                                              const bf16* __restrict__ WT,
                                              const bf16* __restrict__ Cb,
                                              const float* __restrict__ bias,
                                              bf16* __restrict__ xt,
                                              bf16* __restrict__ xc,
                                              bf16* __restrict__ xtT) {
    __shared__ bf16 ldsA_all[4][32 * 40];
    __shared__ bf16 ldsB_all[4][32 * 40];
    int bid = blockIdx.x;
    int ntg = bid & 15, h = (bid >> 4) & 7, b = bid >> 7;
    int wave = threadIdx.x >> 6;
    int lane = threadIdx.x & 63;
    int nt = ntg * 4 + wave;
    int n0 = nt * 32;
    int c = lane & 15, q = lane >> 4;
    bf16* ldsA = ldsA_all[wave];
    bf16* ldsB = ldsB_all[wave];

    f32x4 acc[2][2] = {};
    const bf16* xrow0 = xbf + ((size_t)(b * NN + n0 + c) * IND + q * 8);
    const bf16* xrow1 = xbf + ((size_t)(b * NN + n0 + 16 + c) * IND + q * 8);
    const bf16* wrow0 = WT + ((h * 32 + c) * IND + q * 8);
    const bf16* wrow1 = WT + ((h * 32 + 16 + c) * IND + q * 8);
#pragma unroll
    for (int k0 = 0; k0 < IND; k0 += 32) {
        bf16x8 a0 = *(const bf16x8*)(xrow0 + k0);
        bf16x8 a1 = *(const bf16x8*)(xrow1 + k0);
        bf16x8 w0 = *(const bf16x8*)(wrow0 + k0);
        bf16x8 w1 = *(const bf16x8*)(wrow1 + k0);
        acc[0][0] = MFMA(a0, w0, acc[0][0]);
        acc[0][1] = MFMA(a0, w1, acc[0][1]);
        acc[1][0] = MFMA(a1, w0, acc[1][0]);
        acc[1][1] = MFMA(a1, w1, acc[1][1]);
    }
    float bv[2] = { bias[h * 32 + c], bias[h * 32 + 16 + c] };
    size_t bh = (size_t)(b * HH + h);
    // C/D layout: row(n_local) = q*4+r (+16*nq), col(o_local) = c (+16*oq)
#pragma unroll
    for (int nq = 0; nq < 2; ++nq)
#pragma unroll
        for (int oq = 0; oq < 2; ++oq)
#pragma unroll
            for (int r = 0; r < 4; ++r)
                ldsA[(nq * 16 + q * 4 + r) * 40 + oq * 16 + c] =
                    (bf16)(acc[nq][oq][r] + bv[oq]);
    // xC = xt @ C^T : B[k=o][col=p] = C[p][o] (row-major C)
    f32x4 acc2[2][2] = {};
    bf16x8 aL0 = *(const bf16x8*)(ldsA + (c) * 40 + q * 8);
    bf16x8 aL1 = *(const bf16x8*)(ldsA + (16 + c) * 40 + q * 8);
    bf16x8 c0 = *(const bf16x8*)(Cb + h * 1024 + (c) * 32 + q * 8);
    bf16x8 c1 = *(const bf16x8*)(Cb + h * 1024 + (16 + c) * 32 + q * 8);
    acc2[0][0] = MFMA(aL0, c0, acc2[0][0]);
    acc2[0][1] = MFMA(aL0, c1, acc2[0][1]);
    acc2[1][0] = MFMA(aL1, c0, acc2[1][0]);
    acc2[1][1] = MFMA(aL1, c1, acc2[1][1]);
#pragma unroll
    for (int nq = 0; nq < 2; ++nq)
#pragma unroll
        for (int pq = 0; pq < 2; ++pq)
#pragma unroll
            for (int r = 0; r < 4; ++r)
                ldsB[(nq * 16 + q * 4 + r) * 40 + pq * 16 + c] =
                    (bf16)acc2[nq][pq][r];

    // ---- coalesced stores from LDS (per-wave, no cross-wave deps) ----
    {
        int n = lane >> 1, half = lane & 1;
        bf16x8 t0 = *(const bf16x8*)(ldsA + n * 40 + half * 16);
        bf16x8 t1 = *(const bf16x8*)(ldsA + n * 40 + half * 16 + 8);
        bf16* dst = xt + (bh * NN + n0 + n) * ATN + half * 16;
        *(bf16x8*)(dst) = t0;
        *(bf16x8*)(dst + 8) = t1;
        bf16x8 u0 = *(const bf16x8*)(ldsB + n * 40 + half * 16);
        bf16x8 u1 = *(const bf16x8*)(ldsB + n * 40 + half * 16 + 8);
        bf16* dst2 = xc + (bh * NN + n0 + n) * ATN + half * 16;
        *(bf16x8*)(dst2) = u0;
        *(bf16x8*)(dst2 + 8) = u1;
    }
    {
        int o = lane >> 1, nh = lane & 1;
        bf16x8 t0, t1;
#pragma unroll
        for (int i = 0; i < 8; ++i) {
            t0[i] = ldsA[(nh * 16 + i) * 40 + o];
            t1[i] = ldsA[(nh * 16 + 8 + i) * 40 + o];
        }
        bf16* dst = xtT + (bh * ATN + o) * NN + n0 + nh * 16;
        *(bf16x8*)(dst) = t0;
        *(bf16x8*)(dst + 8) = t1;
    }
}

// ---------------- kernel B: fused scores/tanh/PV, software-pipelined ----------------
// grid 1024 = chunk(4) * b(4) * ntile(64); 512 thr = 8 waves; wave == head.
// Register double-buffer: iteration i issues tile i+1's global loads (adj,
// xt, xtT) before computing tile i -> each load gets a full iteration
// (~450+ cyc of tanh/MFMA/LDS) in flight instead of ~0.
__global__ __launch_bounds__(512, 4) void k_attn(const float* __restrict__ adj,
                                                 const bf16* __restrict__ xt,
                                                 const bf16* __restrict__ xc,
                                                 const bf16* __restrict__ xtT,
                                                 float* __restrict__ out) {
    __shared__ ushort alds[HH * 32 * 40];   // per-wave alpha tile, 80 B stride
    int bid = blockIdx.x;
    int chunk = bid >> 8;
    int bn = bid & 255;
    int nt = bn & 63, b = bn >> 6;
    int n0 = nt * 32;
    int wave = threadIdx.x >> 6;            // == head
    int lane = threadIdx.x & 63;
    int c = lane & 15, q = lane >> 4;
    size_t bh = (size_t)(b * HH + wave);
    const bf16* xt_h = xt + bh * NN * ATN;
    const bf16* xc_h = xc + bh * NN * ATN;
    const bf16* xtT_h = xtT + bh * ATN * NN;
    const float* adj_b = adj + (size_t)b * NN * NN;
    bf16* al = (bf16*)(alds + wave * 32 * 40);

    // scores B-operand: B[k=p][col=n] = xC[n][p], fixed n-tile -> preload
    bf16x8 bXC0 = *(const bf16x8*)(xc_h + (n0 + c) * ATN + q * 8);
    bf16x8 bXC1 = *(const bf16x8*)(xc_h + (n0 + 16 + c) * ATN + q * 8);
    f32x4 accO[2][2] = {};
    const f32x4 z = {0.f, 0.f, 0.f, 0.f};

    const int m_beg = chunk * 512;

    // double-buffered per-tile inputs
    bf16x8 aXT[2][2];          // scores A: xt rows m
    bf16x8 bXT[2][2];          // PV B: xtT[o][m]
    f32x4  adjv[2][4];         // adj[n][m], index nq*2+mq

#define LOAD_TILE(buf, m0) do {                                               \
        aXT[buf][0] = *(const bf16x8*)(xt_h + ((m0) + c) * ATN + q * 8);      \
        aXT[buf][1] = *(const bf16x8*)(xt_h + ((m0) + 16 + c) * ATN + q * 8); \
        bXT[buf][0] = *(const bf16x8*)(xtT_h + (c) * NN + (m0) + q * 8);      \
        bXT[buf][1] = *(const bf16x8*)(xtT_h + (16 + c) * NN + (m0) + q * 8); \
        adjv[buf][0] = *(const f32x4*)(adj_b + (size_t)(n0 + c) * NN + (m0) + q * 4);            \
        adjv[buf][1] = *(const f32x4*)(adj_b + (size_t)(n0 + c) * NN + (m0) + 16 + q * 4);       \
        adjv[buf][2] = *(const f32x4*)(adj_b + (size_t)(n0 + 16 + c) * NN + (m0) + q * 4);       \
        adjv[buf][3] = *(const f32x4*)(adj_b + (size_t)(n0 + 16 + c) * NN + (m0) + 16 + q * 4);  \
    } while (0)

    LOAD_TILE(0, m_beg);
#pragma unroll
    for (int i = 0; i < 16; ++i) {
        const int cur = i & 1, nxt = cur ^ 1;
        const int m0 = m_beg + i * 32;
        if (i < 15) LOAD_TILE(nxt, m0 + 32);   // prefetch next tile

        f32x4 S[2][2];
        S[0][0] = MFMA(aXT[cur][0], bXC0, z);
        S[0][1] = MFMA(aXT[cur][0], bXC1, z);
        S[1][0] = MFMA(aXT[cur][1], bXC0, z);
        S[1][1] = MFMA(aXT[cur][1], bXC1, z);
        // S' D layout: row = m_local = q*4+r (+16mq), col = n_local = c (+16nq)
#pragma unroll
        for (int mq = 0; mq < 2; ++mq)
#pragma unroll
            for (int nq = 0; nq < 2; ++nq) {
                f32x4 av = adjv[cur][nq * 2 + mq];
                bf16x4 pk;
#pragma unroll
                for (int r = 0; r < 4; ++r)
                    pk[r] = (bf16)fast_tanh(S[mq][nq][r] * av[r]);
                *(bf16x4*)(al + (nq * 16 + c) * 40 + mq * 16 + q * 4) = pk;
            }
        // PV: A[n][k=m] from LDS, B[k=m][col=o] = xtT[o][m]
        bf16x8 aAL0 = *(const bf16x8*)(al + (c) * 40 + q * 8);
        bf16x8 aAL1 = *(const bf16x8*)(al + (16 + c) * 40 + q * 8);
        accO[0][0] = MFMA(aAL0, bXT[cur][0], accO[0][0]);
        accO[0][1] = MFMA(aAL0, bXT[cur][1], accO[0][1]);
        accO[1][0] = MFMA(aAL1, bXT[cur][0], accO[1][0]);
        accO[1][1] = MFMA(aAL1, bXT[cur][1], accO[1][1]);
    }
#undef LOAD_TILE

    // epilogue: accumulate across chunks with native f32 atomics
#pragma unroll
    for (int nq = 0; nq < 2; ++nq)
#pragma unroll
        for (int oq = 0; oq < 2; ++oq)
#pragma unroll
            for (int r = 0; r < 4; ++r) {
                int n = n0 + nq * 16 + q * 4 + r;
                int o = wave * 32 + oq * 16 + c;
                unsafeAtomicAdd(&out[((size_t)b * NN + n) * (HH * ATN) + o],
                                accO[nq][oq][r]);
            }
}

extern "C" void kernel_launch(void* const* d_in, const int* in_sizes, int n_in,
                              void* d_out, int out_size, void* d_ws, size_t ws_size,
                              hipStream_t stream) {
    const float* x    = (const float*)d_in[0];   // [4,2048,256]
    const float* adj  = (const float*)d_in[1];   // [4,2048,2048]
    const float* W    = (const float*)d_in[2];   // [8,256,32]
    const float* bias = (const float*)d_in[3];   // [8,32]
    const float* C    = (const float*)d_in[4];   // [8,32,32]
    float* out = (float*)d_out;                  // [4,2048,256]

    char* ws = (char*)d_ws;                      // ~16.9 MB
    bf16* xbf = (bf16*)(ws + OFF_XBF);
    bf16* xt  = (bf16*)(ws + OFF_XT);
    bf16* xc  = (bf16*)(ws + OFF_XC);
    bf16* xtT = (bf16*)(ws + OFF_XTT);
    bf16* WT  = (bf16*)(ws + OFF_WT);
    bf16* Cb  = (bf16*)(ws + OFF_CB);

    k_prep<<<4384, 256, 0, stream>>>(x, W, C, xbf, WT, Cb, out);
    k_proj<<<512, 256, 0, stream>>>(xbf, WT, Cb, bias, xt, xc, xtT);
    k_attn<<<1024, 512, 0, stream>>>(adj, xt, xc, xtT, out);
}